// Round 4
// baseline (138.000 us; speedup 1.0000x reference)
//
#include <hip/hip_runtime.h>
#include <math.h>

#define N_NODES 1024
#define T_STEPS 36
#define KTILE   128          // k-nodes per attn V tile
#define VTSTR   136          // V^T LDS row stride (bf16): 128 data + 8 pad
#define WOS     72           // outproj Wo LDS stride (bf16)
#define OBS2    72           // outproj ob-tile LDS stride (bf16)
#define YSTR    67           // proj LDS row stride (uint32)

typedef __bf16  bf16x8 __attribute__((ext_vector_type(8)));
typedef float   f32x4  __attribute__((ext_vector_type(4)));

#define MFMA_BF16 __builtin_amdgcn_mfma_f32_16x16x32_bf16
#define PERM_HI 0x07060302u   // (a,b) -> hi16(b) | hi16(a)<<16
#define PERM_LO 0x05040100u   // (a,b) -> lo16(b) | lo16(a)<<16

__device__ __forceinline__ unsigned short bf16_rne(float f) {
    unsigned int u = __float_as_uint(f);
    u += 0x7FFFu + ((u >> 16) & 1u);
    return (unsigned short)(u >> 16);
}
__device__ __forceinline__ float bf16_tof(unsigned short h) {
    return __uint_as_float(((unsigned int)h) << 16);
}
// fp32 -> (hi bf16 << 16) | lo bf16, hi/lo split
__device__ __forceinline__ unsigned int split_pack(float a) {
    unsigned short hi = bf16_rne(a);
    unsigned short lo = bf16_rne(a - bf16_tof(hi));
    return ((unsigned int)hi << 16) | lo;
}

// ---------------------------------------------------------------------------
// Kernel 1 (proj6): R12 threading of the R5 structure (neutral vs proj5;
// kept — simpler per-thread body, bit-identical output). UNCHANGED in R13.
// ---------------------------------------------------------------------------
__global__ __launch_bounds__(512, 8) void proj6_kernel(
    const float* __restrict__ vin, const float* __restrict__ kin, const float* __restrict__ qin,
    const float* __restrict__ Wv, const float* __restrict__ Wk, const float* __restrict__ Wq,
    unsigned short* __restrict__ qhi, unsigned short* __restrict__ qlo,
    unsigned short* __restrict__ khi, unsigned short* __restrict__ klo,
    unsigned short* __restrict__ vthi, unsigned short* __restrict__ vtlo)
{
    __shared__ float sW[256];
    __shared__ unsigned int ys[128 * YSTR];   // [row(nl*2+tl)][hd*16+e] packed hi|lo

    const int tid = threadIdx.x;
    const int mat = blockIdx.y;               // 0=v, 1=k, 2=q
    const int nt  = blockIdx.x & 15;
    const int tt  = blockIdx.x >> 4;          // 0..17
    const int n0  = nt * 64, t0 = tt * 2;

    const float* in = (mat == 0) ? vin : (mat == 1) ? kin : qin;
    const float* W  = (mat == 0) ? Wv  : (mat == 1) ? Wk  : Wq;
    if (tid < 256) sW[tid] = W[tid];
    __syncthreads();

    // ---- Phase A: thread = (row, head). 16 loads, 256 FMAs, 16 packs ----
    {
        const int r  = tid >> 2;              // 0..127 = nl*2 + tl
        const int hd = tid & 3;
        const int nl = r >> 1, tl = r & 1;
        const size_t p = ((size_t)(n0 + nl)) * T_STEPS + (t0 + tl);
        const float4* src = (const float4*)(in + p * 64 + hd * 16);
        float x[16];
        #pragma unroll
        for (int i = 0; i < 4; ++i) {
            float4 f = src[i];
            x[4*i] = f.x; x[4*i+1] = f.y; x[4*i+2] = f.z; x[4*i+3] = f.w;
        }
        const float scale = (mat == 2) ? 0.18033688011112042f : 1.0f;  // log2(e)/8 on Q
        unsigned int* yrow = &ys[r * YSTR + hd * 16];
        #pragma unroll
        for (int e = 0; e < 16; ++e) {
            float4 w0 = *(const float4*)&sW[e*16+0],  w1 = *(const float4*)&sW[e*16+4];
            float4 w2 = *(const float4*)&sW[e*16+8],  w3 = *(const float4*)&sW[e*16+12];
            float a = x[0]*w0.x;
            a = fmaf(x[1],w0.y,a);  a = fmaf(x[2],w0.z,a);  a = fmaf(x[3],w0.w,a);
            a = fmaf(x[4],w1.x,a);  a = fmaf(x[5],w1.y,a);  a = fmaf(x[6],w1.z,a);  a = fmaf(x[7],w1.w,a);
            a = fmaf(x[8],w2.x,a);  a = fmaf(x[9],w2.y,a);  a = fmaf(x[10],w2.z,a); a = fmaf(x[11],w2.w,a);
            a = fmaf(x[12],w3.x,a); a = fmaf(x[13],w3.y,a); a = fmaf(x[14],w3.z,a); a = fmaf(x[15],w3.w,a);
            yrow[e] = split_pack(a * scale);
        }
    }
    __syncthreads();

    // ---- Phase B: coalesced writes; 4 groups x 2 passes = same 8 passes ----
    const int tid2 = tid & 127;
    const int pgrp = tid >> 7;                // 0..3
    if (mat != 0) {
        unsigned short* ohi = (mat == 1) ? khi : qhi;
        unsigned short* olo = (mat == 1) ? klo : qlo;
        const int nl2 = tid2 >> 1, eh = tid2 & 1;
        #pragma unroll
        for (int i = 0; i < 2; ++i) {
            const int pass = pgrp * 2 + i;
            const int tl2 = pass & 1, hd = pass >> 1;
            const unsigned int* yr = &ys[(nl2*2 + tl2) * YSTR + hd*16 + eh*8];
            unsigned int u0 = yr[0], u1 = yr[1], u2 = yr[2], u3 = yr[3];
            unsigned int u4 = yr[4], u5 = yr[5], u6 = yr[6], u7 = yr[7];
            uint4 hi4, lo4;
            hi4.x = __builtin_amdgcn_perm(u1, u0, PERM_HI);
            hi4.y = __builtin_amdgcn_perm(u3, u2, PERM_HI);
            hi4.z = __builtin_amdgcn_perm(u5, u4, PERM_HI);
            hi4.w = __builtin_amdgcn_perm(u7, u6, PERM_HI);
            lo4.x = __builtin_amdgcn_perm(u1, u0, PERM_LO);
            lo4.y = __builtin_amdgcn_perm(u3, u2, PERM_LO);
            lo4.z = __builtin_amdgcn_perm(u5, u4, PERM_LO);
            lo4.w = __builtin_amdgcn_perm(u7, u6, PERM_LO);
            const int th = (t0 + tl2) * 4 + hd;
            const size_t off = ((size_t)th * N_NODES + n0 + nl2) * 16 + eh * 8;
            *(uint4*)(ohi + off) = hi4;
            *(uint4*)(olo + off) = lo4;
        }
    } else {
        const int e = tid2 >> 3, ng = tid2 & 7;
        #pragma unroll
        for (int i = 0; i < 2; ++i) {
            const int pass = pgrp * 2 + i;
            const int tl2 = pass & 1, hd = pass >> 1;
            unsigned int u[8];
            #pragma unroll
            for (int j = 0; j < 8; ++j)
                u[j] = ys[((ng*8 + j)*2 + tl2) * YSTR + hd*16 + e];
            uint4 hi4, lo4;
            hi4.x = __builtin_amdgcn_perm(u[1], u[0], PERM_HI);
            hi4.y = __builtin_amdgcn_perm(u[3], u[2], PERM_HI);
            hi4.z = __builtin_amdgcn_perm(u[5], u[4], PERM_HI);
            hi4.w = __builtin_amdgcn_perm(u[7], u[6], PERM_HI);
            lo4.x = __builtin_amdgcn_perm(u[1], u[0], PERM_LO);
            lo4.y = __builtin_amdgcn_perm(u[3], u[2], PERM_LO);
            lo4.z = __builtin_amdgcn_perm(u[5], u[4], PERM_LO);
            lo4.w = __builtin_amdgcn_perm(u[7], u[6], PERM_LO);
            const int th = (t0 + tl2) * 4 + hd;
            const size_t off = ((size_t)th * 16 + e) * N_NODES + n0 + ng * 8;
            *(uint4*)(vthi + off) = hi4;
            *(uint4*)(vtlo + off) = lo4;
        }
    }
}

// ---------------------------------------------------------------------------
// Kernel 2 (attn_mfma8): R13 — double-buffered V staging.
//  attn7 was stall-bound (all pipes <= 8us chip-wide vs ~42us runtime); the
//  serializer was 2 barriers/KTILE with the V prefetch consumed right at the
//  barrier boundary. New schedule per tile i:
//      write tile i -> ONE barrier -> issue prefetch i+1 -> compute tile i
//  Hazards checked: writer of buf[(i+1)&1] has passed barrier_i, which
//  happens-after every wave's compute_{i-1} on that same buffer.
//  Barriers 16 -> 8; prefetch hidden under full compute phase.
//  LDS 17.4KB, 8 blocks/CU (139KB/CU) -> occupancy preserved. Math identical.
// ---------------------------------------------------------------------------
__global__ __launch_bounds__(256, 8) void attn_mfma8_kernel(
    const unsigned short* __restrict__ qhi, const unsigned short* __restrict__ qlo,
    const unsigned short* __restrict__ khi, const unsigned short* __restrict__ klo,
    const unsigned short* __restrict__ vthi, const unsigned short* __restrict__ vtlo,
    unsigned short* __restrict__ obh, unsigned short* __restrict__ obl)
{
    __shared__ unsigned short vs[2][2][16 * VTSTR];   // [buf][plane(hi,lo)][...]

    const int tid  = threadIdx.x;
    const int wave = tid >> 6, lane = tid & 63;
    const int m = lane & 15, quad = lane >> 4;

    const int bid = blockIdx.x;
    const int th  = bid % 144;          // th mod 8 stable -> XCD-local K/V reuse
    const int qb  = bid / 144;
    const int t   = th >> 2, hd = th & 3;
    const int q0  = qb * 64;
    const size_t base_th = (size_t)th * N_NODES;

    bf16x8 b1q, b2q;
    {
        const int qrow = q0 + wave * 16 + m;
        b1q = *(const bf16x8*)(qhi + (base_th + qrow) * 16 + (quad & 1) * 8);
        b2q = *(const bf16x8*)(qlo + (base_th + qrow) * 16 + (quad & 1) * 8);
    }

    union { unsigned short su[8]; bf16x8 v; } onesu;
    #pragma unroll
    for (int i = 0; i < 8; ++i) onesu.su[i] = 0x3F80;
    const bf16x8 bones = onesu.v;

    f32x4 og   = {0.f,0.f,0.f,0.f};
    f32x4 lacc = {0.f,0.f,0.f,0.f};

    const unsigned short* kfrag = ((quad < 2) ? khi : klo)
        + (base_th + m) * 16 + (quad & 1) * 8;

    // V staging: plane = tid>>7 (waves 0,1 -> hi; 2,3 -> lo); 128 thr/plane,
    // each thread stages 16 shorts (half a 32-chunk). Same src->dst
    // permutation as attn7.
    const int p     = tid & 127;
    const int pl    = tid >> 7;
    const int vd    = p >> 3;          // 0..15 dim row
    const int vpart = (p >> 1) & 3;    // 32-chunk within 128-node tile
    const int half  = p & 1;           // 0: src nodes 0-15 / 1: src nodes 16-31
    const unsigned short* vsrc0 = (pl ? vtlo : vthi)
        + ((size_t)th * 16 + vd) * N_NODES + vpart * 32 + half * 16;
    const int vdoff = vd * VTSTR + vpart * 32 + half * 4;

    uint4 pf0, pf1;
    { const uint4* s = (const uint4*)vsrc0; pf0 = s[0]; pf1 = s[1]; }

    for (int kt = 0; kt < N_NODES; kt += KTILE) {
        const int buf = (kt >> 7) & 1;
        unsigned short* vdst = &vs[buf][pl][vdoff];
        *(uint2*)&vdst[0]  = make_uint2(pf0.x, pf0.y);
        *(uint2*)&vdst[8]  = make_uint2(pf0.z, pf0.w);
        *(uint2*)&vdst[16] = make_uint2(pf1.x, pf1.y);
        *(uint2*)&vdst[24] = make_uint2(pf1.z, pf1.w);
        __syncthreads();
        if (kt + KTILE < N_NODES) {
            const uint4* s = (const uint4*)(vsrc0 + kt + KTILE);
            pf0 = s[0]; pf1 = s[1];
        }
        const unsigned short* vhs = &vs[buf][0][0];
        const unsigned short* vls = &vs[buf][1][0];

        #pragma unroll
        for (int c = 0; c < 4; ++c) {
            bf16x8 a0 = *(const bf16x8*)(kfrag + (size_t)(kt + (2*c    )*16) * 16);
            bf16x8 a1 = *(const bf16x8*)(kfrag + (size_t)(kt + (2*c + 1)*16) * 16);
            bf16x8 vh = *(const bf16x8*)&vhs[m * VTSTR + quad * 8 + c * 32];
            bf16x8 vl = *(const bf16x8*)&vls[m * VTSTR + quad * 8 + c * 32];
            f32x4 s0 = MFMA_BF16(a0, b1q, (f32x4){0.f,0.f,0.f,0.f}, 0, 0, 0);
            s0 = MFMA_BF16(a0, b2q, s0, 0, 0, 0);
            f32x4 s1 = MFMA_BF16(a1, b1q, (f32x4){0.f,0.f,0.f,0.f}, 0, 0, 0);
            s1 = MFMA_BF16(a1, b2q, s1, 0, 0, 0);
            union { __bf16 b[8]; bf16x8 v; } ap;
            ap.b[0] = (__bf16)__builtin_amdgcn_exp2f(s0[0]);
            ap.b[1] = (__bf16)__builtin_amdgcn_exp2f(s0[1]);
            ap.b[2] = (__bf16)__builtin_amdgcn_exp2f(s0[2]);
            ap.b[3] = (__bf16)__builtin_amdgcn_exp2f(s0[3]);
            ap.b[4] = (__bf16)__builtin_amdgcn_exp2f(s1[0]);
            ap.b[5] = (__bf16)__builtin_amdgcn_exp2f(s1[1]);
            ap.b[6] = (__bf16)__builtin_amdgcn_exp2f(s1[2]);
            ap.b[7] = (__bf16)__builtin_amdgcn_exp2f(s1[3]);
            lacc = MFMA_BF16(ap.v, bones, lacc, 0, 0, 0);
            og   = MFMA_BF16(ap.v, vh, og, 0, 0, 0);
            og   = MFMA_BF16(ap.v, vl, og, 0, 0, 0);
        }
    }

    #pragma unroll
    for (int r = 0; r < 4; ++r) {
        const float val = og[r] * __builtin_amdgcn_rcpf(lacc[r]);
        const int row = q0 + wave * 16 + quad * 4 + r;
        const size_t off = ((size_t)row * T_STEPS + t) * 64 + hd * 16 + m;
        unsigned short hh = bf16_rne(val);
        obh[off] = hh;
        obl[off] = bf16_rne(val - bf16_tof(hh));
    }
}

// ---------------------------------------------------------------------------
// Kernel 3: MFMA output projection (unchanged).
// ---------------------------------------------------------------------------
__global__ __launch_bounds__(256) void outproj_mfma_kernel(
    const unsigned short* __restrict__ obh, const unsigned short* __restrict__ obl,
    const float* __restrict__ Wo, const float* __restrict__ bo,
    float* __restrict__ out)
{
    __shared__ unsigned short woh[64 * WOS], wol[64 * WOS];
    __shared__ unsigned short oth[64 * OBS2], otl[64 * OBS2];
    __shared__ float sb[64];
    const int tid = threadIdx.x;

    #pragma unroll
    for (int i = 0; i < 16; ++i) {
        int idx = tid + 256 * i;
        int r = idx >> 6, c = idx & 63;
        float w = Wo[idx];
        unsigned short hh = bf16_rne(w);
        woh[r * WOS + c] = hh;
        wol[r * WOS + c] = bf16_rne(w - bf16_tof(hh));
    }
    if (tid < 64) sb[tid] = bo[tid];

    const size_t p0 = (size_t)blockIdx.x * 64;
    #pragma unroll
    for (int i = 0; i < 2; ++i) {
        int idx = tid + 256 * i;
        int r = idx >> 3, c = (idx & 7) * 8;
        *(uint4*)&oth[r * OBS2 + c] = *(const uint4*)(obh + (p0 + r) * 64 + c);
        *(uint4*)&otl[r * OBS2 + c] = *(const uint4*)(obl + (p0 + r) * 64 + c);
    }
    __syncthreads();

    const int wave = tid >> 6, lane = tid & 63;
    const int m = lane & 15, quad = lane >> 4;
    const int r0 = wave * 16;

    bf16x8 ah[2], al[2];
    #pragma unroll
    for (int kh = 0; kh < 2; ++kh) {
        ah[kh] = *(const bf16x8*)&oth[(r0 + m) * OBS2 + kh * 32 + quad * 8];
        al[kh] = *(const bf16x8*)&otl[(r0 + m) * OBS2 + kh * 32 + quad * 8];
    }

    f32x4 acc[4] = {{0,0,0,0},{0,0,0,0},{0,0,0,0},{0,0,0,0}};
    #pragma unroll
    for (int jt = 0; jt < 4; ++jt) {
        #pragma unroll
        for (int kh = 0; kh < 2; ++kh) {
            bf16x8 bh = *(const bf16x8*)&woh[(jt * 16 + m) * WOS + kh * 32 + quad * 8];
            bf16x8 bl = *(const bf16x8*)&wol[(jt * 16 + m) * WOS + kh * 32 + quad * 8];
            acc[jt] = MFMA_BF16(ah[kh], bh, acc[jt], 0, 0, 0);
            acc[jt] = MFMA_BF16(al[kh], bh, acc[jt], 0, 0, 0);
            acc[jt] = MFMA_BF16(ah[kh], bl, acc[jt], 0, 0, 0);
        }
    }

    #pragma unroll
    for (int jt = 0; jt < 4; ++jt) {
        const float b = sb[jt * 16 + m];
        #pragma unroll
        for (int r = 0; r < 4; ++r)
            out[(p0 + r0 + quad * 4 + r) * 64 + jt * 16 + m] = acc[jt][r] + b;
    }
}

// ---------------------------------------------------------------------------
extern "C" void kernel_launch(void* const* d_in, const int* in_sizes, int n_in,
                              void* d_out, int out_size, void* d_ws, size_t ws_size,
                              hipStream_t stream)
{
    (void)in_sizes; (void)n_in; (void)out_size; (void)ws_size;
    const float* values = (const float*)d_in[0];
    const float* keys   = (const float*)d_in[1];
    const float* query  = (const float*)d_in[2];
    const float* Wv     = (const float*)d_in[3];
    const float* Wk     = (const float*)d_in[4];
    const float* Wq     = (const float*)d_in[5];
    const float* Wo     = (const float*)d_in[6];
    const float* bo     = (const float*)d_in[7];

    const size_t TOT = (size_t)144 * N_NODES * 16;   // 2,359,296 bf16 per plane
    unsigned short* ws16 = (unsigned short*)d_ws;
    unsigned short* qhi  = ws16;
    unsigned short* qlo  = ws16 + 1*TOT;
    unsigned short* khi  = ws16 + 2*TOT;
    unsigned short* klo  = ws16 + 3*TOT;
    unsigned short* vthi = ws16 + 4*TOT;
    unsigned short* vtlo = ws16 + 5*TOT;
    unsigned short* obh  = ws16 + 6*TOT;
    unsigned short* obl  = ws16 + 7*TOT;             // total ws = 8*TOT*2B = 37.75 MB

    // 288 = 16 n-tiles x 18 t-tiles; y = matrix (0=v,1=k,2=q)
    proj6_kernel<<<dim3(288, 3), 512, 0, stream>>>(values, keys, query, Wv, Wk, Wq,
                                                   qhi, qlo, khi, klo, vthi, vtlo);
    attn_mfma8_kernel<<<dim3(16 * 144), 256, 0, stream>>>(qhi, qlo, khi, klo, vthi, vtlo,
                                                          obh, obl);
    outproj_mfma_kernel<<<dim3(576), 256, 0, stream>>>(obh, obl, Wo, bo, (float*)d_out);
}

// Round 5
// 133.982 us; speedup vs baseline: 1.0300x; 1.0300x over previous
//
#include <hip/hip_runtime.h>
#include <math.h>

#define N_NODES 1024
#define T_STEPS 36
#define KTILE   128          // k-nodes per attn V tile
#define VTSTR   136          // V^T LDS row stride (bf16): 128 data + 8 pad
#define WOS     72           // outproj Wo LDS stride (bf16)
#define OBS2    72           // outproj ob-tile LDS stride (bf16)
#define YSTR    67           // proj LDS row stride (uint32)

typedef __bf16  bf16x8 __attribute__((ext_vector_type(8)));
typedef float   f32x4  __attribute__((ext_vector_type(4)));

#define MFMA_BF16 __builtin_amdgcn_mfma_f32_16x16x32_bf16
#define PERM_HI 0x07060302u   // (a,b) -> hi16(b) | hi16(a)<<16
#define PERM_LO 0x05040100u   // (a,b) -> lo16(b) | lo16(a)<<16

__device__ __forceinline__ unsigned short bf16_rne(float f) {
    unsigned int u = __float_as_uint(f);
    u += 0x7FFFu + ((u >> 16) & 1u);
    return (unsigned short)(u >> 16);
}
__device__ __forceinline__ float bf16_tof(unsigned short h) {
    return __uint_as_float(((unsigned int)h) << 16);
}
// fp32 -> (hi bf16 << 16) | lo bf16, hi/lo split
__device__ __forceinline__ unsigned int split_pack(float a) {
    unsigned short hi = bf16_rne(a);
    unsigned short lo = bf16_rne(a - bf16_tof(hi));
    return ((unsigned int)hi << 16) | lo;
}

// ---------------------------------------------------------------------------
// Kernel 1 (proj6): unchanged (R12 threading of the R5 structure; neutral
// but simpler; bit-identical output).
// ---------------------------------------------------------------------------
__global__ __launch_bounds__(512, 8) void proj6_kernel(
    const float* __restrict__ vin, const float* __restrict__ kin, const float* __restrict__ qin,
    const float* __restrict__ Wv, const float* __restrict__ Wk, const float* __restrict__ Wq,
    unsigned short* __restrict__ qhi, unsigned short* __restrict__ qlo,
    unsigned short* __restrict__ khi, unsigned short* __restrict__ klo,
    unsigned short* __restrict__ vthi, unsigned short* __restrict__ vtlo)
{
    __shared__ float sW[256];
    __shared__ unsigned int ys[128 * YSTR];   // [row(nl*2+tl)][hd*16+e] packed hi|lo

    const int tid = threadIdx.x;
    const int mat = blockIdx.y;               // 0=v, 1=k, 2=q
    const int nt  = blockIdx.x & 15;
    const int tt  = blockIdx.x >> 4;          // 0..17
    const int n0  = nt * 64, t0 = tt * 2;

    const float* in = (mat == 0) ? vin : (mat == 1) ? kin : qin;
    const float* W  = (mat == 0) ? Wv  : (mat == 1) ? Wk  : Wq;
    if (tid < 256) sW[tid] = W[tid];
    __syncthreads();

    // ---- Phase A: thread = (row, head). 16 loads, 256 FMAs, 16 packs ----
    {
        const int r  = tid >> 2;              // 0..127 = nl*2 + tl
        const int hd = tid & 3;
        const int nl = r >> 1, tl = r & 1;
        const size_t p = ((size_t)(n0 + nl)) * T_STEPS + (t0 + tl);
        const float4* src = (const float4*)(in + p * 64 + hd * 16);
        float x[16];
        #pragma unroll
        for (int i = 0; i < 4; ++i) {
            float4 f = src[i];
            x[4*i] = f.x; x[4*i+1] = f.y; x[4*i+2] = f.z; x[4*i+3] = f.w;
        }
        const float scale = (mat == 2) ? 0.18033688011112042f : 1.0f;  // log2(e)/8 on Q
        unsigned int* yrow = &ys[r * YSTR + hd * 16];
        #pragma unroll
        for (int e = 0; e < 16; ++e) {
            float4 w0 = *(const float4*)&sW[e*16+0],  w1 = *(const float4*)&sW[e*16+4];
            float4 w2 = *(const float4*)&sW[e*16+8],  w3 = *(const float4*)&sW[e*16+12];
            float a = x[0]*w0.x;
            a = fmaf(x[1],w0.y,a);  a = fmaf(x[2],w0.z,a);  a = fmaf(x[3],w0.w,a);
            a = fmaf(x[4],w1.x,a);  a = fmaf(x[5],w1.y,a);  a = fmaf(x[6],w1.z,a);  a = fmaf(x[7],w1.w,a);
            a = fmaf(x[8],w2.x,a);  a = fmaf(x[9],w2.y,a);  a = fmaf(x[10],w2.z,a); a = fmaf(x[11],w2.w,a);
            a = fmaf(x[12],w3.x,a); a = fmaf(x[13],w3.y,a); a = fmaf(x[14],w3.z,a); a = fmaf(x[15],w3.w,a);
            yrow[e] = split_pack(a * scale);
        }
    }
    __syncthreads();

    // ---- Phase B: coalesced writes; 4 groups x 2 passes = same 8 passes ----
    const int tid2 = tid & 127;
    const int pgrp = tid >> 7;                // 0..3
    if (mat != 0) {
        unsigned short* ohi = (mat == 1) ? khi : qhi;
        unsigned short* olo = (mat == 1) ? klo : qlo;
        const int nl2 = tid2 >> 1, eh = tid2 & 1;
        #pragma unroll
        for (int i = 0; i < 2; ++i) {
            const int pass = pgrp * 2 + i;
            const int tl2 = pass & 1, hd = pass >> 1;
            const unsigned int* yr = &ys[(nl2*2 + tl2) * YSTR + hd*16 + eh*8];
            unsigned int u0 = yr[0], u1 = yr[1], u2 = yr[2], u3 = yr[3];
            unsigned int u4 = yr[4], u5 = yr[5], u6 = yr[6], u7 = yr[7];
            uint4 hi4, lo4;
            hi4.x = __builtin_amdgcn_perm(u1, u0, PERM_HI);
            hi4.y = __builtin_amdgcn_perm(u3, u2, PERM_HI);
            hi4.z = __builtin_amdgcn_perm(u5, u4, PERM_HI);
            hi4.w = __builtin_amdgcn_perm(u7, u6, PERM_HI);
            lo4.x = __builtin_amdgcn_perm(u1, u0, PERM_LO);
            lo4.y = __builtin_amdgcn_perm(u3, u2, PERM_LO);
            lo4.z = __builtin_amdgcn_perm(u5, u4, PERM_LO);
            lo4.w = __builtin_amdgcn_perm(u7, u6, PERM_LO);
            const int th = (t0 + tl2) * 4 + hd;
            const size_t off = ((size_t)th * N_NODES + n0 + nl2) * 16 + eh * 8;
            *(uint4*)(ohi + off) = hi4;
            *(uint4*)(olo + off) = lo4;
        }
    } else {
        const int e = tid2 >> 3, ng = tid2 & 7;
        #pragma unroll
        for (int i = 0; i < 2; ++i) {
            const int pass = pgrp * 2 + i;
            const int tl2 = pass & 1, hd = pass >> 1;
            unsigned int u[8];
            #pragma unroll
            for (int j = 0; j < 8; ++j)
                u[j] = ys[((ng*8 + j)*2 + tl2) * YSTR + hd*16 + e];
            uint4 hi4, lo4;
            hi4.x = __builtin_amdgcn_perm(u[1], u[0], PERM_HI);
            hi4.y = __builtin_amdgcn_perm(u[3], u[2], PERM_HI);
            hi4.z = __builtin_amdgcn_perm(u[5], u[4], PERM_HI);
            hi4.w = __builtin_amdgcn_perm(u[7], u[6], PERM_HI);
            lo4.x = __builtin_amdgcn_perm(u[1], u[0], PERM_LO);
            lo4.y = __builtin_amdgcn_perm(u[3], u[2], PERM_LO);
            lo4.z = __builtin_amdgcn_perm(u[5], u[4], PERM_LO);
            lo4.w = __builtin_amdgcn_perm(u[7], u[6], PERM_LO);
            const int th = (t0 + tl2) * 4 + hd;
            const size_t off = ((size_t)th * 16 + e) * N_NODES + n0 + ng * 8;
            *(uint4*)(vthi + off) = hi4;
            *(uint4*)(vtlo + off) = lo4;
        }
    }
}

// ---------------------------------------------------------------------------
// Kernel 2 (attn_mfma9): R14.
//  - REVERT R13 double-buffer (was -1.7us) -> attn7's single-buffer schedule.
//  - NEW: 128 q-rows per block (qb = 8 tiles), g=2 loop per wave (attn5's
//    proven body): K-frags a0/a1 and V LDS reads shared across both q-groups.
//    Grid 144*8 = 1152 blocks -> ALL co-resident (4.5 blocks/CU < 8 cap):
//    removes attn7's 256-block dispatch tail (2304 > 2048 resident cap);
//    halves K global traffic and barriers per unit work.
// ---------------------------------------------------------------------------
__global__ __launch_bounds__(256, 4) void attn_mfma9_kernel(
    const unsigned short* __restrict__ qhi, const unsigned short* __restrict__ qlo,
    const unsigned short* __restrict__ khi, const unsigned short* __restrict__ klo,
    const unsigned short* __restrict__ vthi, const unsigned short* __restrict__ vtlo,
    unsigned short* __restrict__ obh, unsigned short* __restrict__ obl)
{
    __shared__ unsigned short vthi_s[16 * VTSTR];   // permuted node order per 32-chunk
    __shared__ unsigned short vtlo_s[16 * VTSTR];

    const int tid  = threadIdx.x;
    const int wave = tid >> 6, lane = tid & 63;
    const int m = lane & 15, quad = lane >> 4;

    const int bid = blockIdx.x;
    const int th  = bid % 144;          // th mod 8 stable -> XCD-local K/V reuse
    const int qb  = bid / 144;          // 0..7
    const int t   = th >> 2, hd = th & 3;
    const int q0  = qb * 128;
    const size_t base_th = (size_t)th * N_NODES;

    bf16x8 b1q[2], b2q[2];
    #pragma unroll
    for (int g = 0; g < 2; ++g) {
        const int qrow = q0 + wave * 32 + g * 16 + m;
        b1q[g] = *(const bf16x8*)(qhi + (base_th + qrow) * 16 + (quad & 1) * 8);
        b2q[g] = *(const bf16x8*)(qlo + (base_th + qrow) * 16 + (quad & 1) * 8);
    }

    union { unsigned short su[8]; bf16x8 v; } onesu;
    #pragma unroll
    for (int i = 0; i < 8; ++i) onesu.su[i] = 0x3F80;
    const bf16x8 bones = onesu.v;

    f32x4 og[2]   = {{0.f,0.f,0.f,0.f},{0.f,0.f,0.f,0.f}};
    f32x4 lacc[2] = {{0.f,0.f,0.f,0.f},{0.f,0.f,0.f,0.f}};

    const unsigned short* kfrag = ((quad < 2) ? khi : klo)
        + (base_th + m) * 16 + (quad & 1) * 8;

    // V staging (attn7's proven 256-thread pattern): plane = tid>>7,
    // 128 thr/plane, each thread stages 16 shorts (half a 32-chunk).
    const int p     = tid & 127;
    const int pl    = tid >> 7;
    const int vd    = p >> 3;          // 0..15 dim row
    const int vpart = (p >> 1) & 3;    // 32-chunk within 128-node tile
    const int half  = p & 1;           // 0: src nodes 0-15 / 1: src nodes 16-31
    const unsigned short* vsrc0 = (pl ? vtlo : vthi)
        + ((size_t)th * 16 + vd) * N_NODES + vpart * 32 + half * 16;
    unsigned short* vdst = (pl ? vtlo_s : vthi_s)
        + vd * VTSTR + vpart * 32 + half * 4;

    uint4 pf0, pf1;
    { const uint4* s = (const uint4*)vsrc0; pf0 = s[0]; pf1 = s[1]; }

    for (int kt = 0; kt < N_NODES; kt += KTILE) {
        __syncthreads();
        *(uint2*)&vdst[0]  = make_uint2(pf0.x, pf0.y);
        *(uint2*)&vdst[8]  = make_uint2(pf0.z, pf0.w);
        *(uint2*)&vdst[16] = make_uint2(pf1.x, pf1.y);
        *(uint2*)&vdst[24] = make_uint2(pf1.z, pf1.w);
        __syncthreads();
        if (kt + KTILE < N_NODES) {
            const uint4* s = (const uint4*)(vsrc0 + kt + KTILE);
            pf0 = s[0]; pf1 = s[1];
        }

        #pragma unroll
        for (int c = 0; c < 4; ++c) {
            bf16x8 a0 = *(const bf16x8*)(kfrag + (size_t)(kt + (2*c    )*16) * 16);
            bf16x8 a1 = *(const bf16x8*)(kfrag + (size_t)(kt + (2*c + 1)*16) * 16);
            bf16x8 vh = *(const bf16x8*)&vthi_s[m * VTSTR + quad * 8 + c * 32];
            bf16x8 vl = *(const bf16x8*)&vtlo_s[m * VTSTR + quad * 8 + c * 32];
            #pragma unroll
            for (int g = 0; g < 2; ++g) {
                f32x4 s0 = MFMA_BF16(a0, b1q[g], (f32x4){0.f,0.f,0.f,0.f}, 0, 0, 0);
                s0 = MFMA_BF16(a0, b2q[g], s0, 0, 0, 0);
                f32x4 s1 = MFMA_BF16(a1, b1q[g], (f32x4){0.f,0.f,0.f,0.f}, 0, 0, 0);
                s1 = MFMA_BF16(a1, b2q[g], s1, 0, 0, 0);
                union { __bf16 b[8]; bf16x8 v; } ap;
                ap.b[0] = (__bf16)__builtin_amdgcn_exp2f(s0[0]);
                ap.b[1] = (__bf16)__builtin_amdgcn_exp2f(s0[1]);
                ap.b[2] = (__bf16)__builtin_amdgcn_exp2f(s0[2]);
                ap.b[3] = (__bf16)__builtin_amdgcn_exp2f(s0[3]);
                ap.b[4] = (__bf16)__builtin_amdgcn_exp2f(s1[0]);
                ap.b[5] = (__bf16)__builtin_amdgcn_exp2f(s1[1]);
                ap.b[6] = (__bf16)__builtin_amdgcn_exp2f(s1[2]);
                ap.b[7] = (__bf16)__builtin_amdgcn_exp2f(s1[3]);
                lacc[g] = MFMA_BF16(ap.v, bones, lacc[g], 0, 0, 0);
                og[g]   = MFMA_BF16(ap.v, vh, og[g], 0, 0, 0);
                og[g]   = MFMA_BF16(ap.v, vl, og[g], 0, 0, 0);
            }
        }
    }

    #pragma unroll
    for (int g = 0; g < 2; ++g) {
        #pragma unroll
        for (int r = 0; r < 4; ++r) {
            const float val = og[g][r] * __builtin_amdgcn_rcpf(lacc[g][r]);
            const int row = q0 + wave * 32 + g * 16 + quad * 4 + r;
            const size_t off = ((size_t)row * T_STEPS + t) * 64 + hd * 16 + m;
            unsigned short hh = bf16_rne(val);
            obh[off] = hh;
            obl[off] = bf16_rne(val - bf16_tof(hh));
        }
    }
}

// ---------------------------------------------------------------------------
// Kernel 3: MFMA output projection (unchanged).
// ---------------------------------------------------------------------------
__global__ __launch_bounds__(256) void outproj_mfma_kernel(
    const unsigned short* __restrict__ obh, const unsigned short* __restrict__ obl,
    const float* __restrict__ Wo, const float* __restrict__ bo,
    float* __restrict__ out)
{
    __shared__ unsigned short woh[64 * WOS], wol[64 * WOS];
    __shared__ unsigned short oth[64 * OBS2], otl[64 * OBS2];
    __shared__ float sb[64];
    const int tid = threadIdx.x;

    #pragma unroll
    for (int i = 0; i < 16; ++i) {
        int idx = tid + 256 * i;
        int r = idx >> 6, c = idx & 63;
        float w = Wo[idx];
        unsigned short hh = bf16_rne(w);
        woh[r * WOS + c] = hh;
        wol[r * WOS + c] = bf16_rne(w - bf16_tof(hh));
    }
    if (tid < 64) sb[tid] = bo[tid];

    const size_t p0 = (size_t)blockIdx.x * 64;
    #pragma unroll
    for (int i = 0; i < 2; ++i) {
        int idx = tid + 256 * i;
        int r = idx >> 3, c = (idx & 7) * 8;
        *(uint4*)&oth[r * OBS2 + c] = *(const uint4*)(obh + (p0 + r) * 64 + c);
        *(uint4*)&otl[r * OBS2 + c] = *(const uint4*)(obl + (p0 + r) * 64 + c);
    }
    __syncthreads();

    const int wave = tid >> 6, lane = tid & 63;
    const int m = lane & 15, quad = lane >> 4;
    const int r0 = wave * 16;

    bf16x8 ah[2], al[2];
    #pragma unroll
    for (int kh = 0; kh < 2; ++kh) {
        ah[kh] = *(const bf16x8*)&oth[(r0 + m) * OBS2 + kh * 32 + quad * 8];
        al[kh] = *(const bf16x8*)&otl[(r0 + m) * OBS2 + kh * 32 + quad * 8];
    }

    f32x4 acc[4] = {{0,0,0,0},{0,0,0,0},{0,0,0,0},{0,0,0,0}};
    #pragma unroll
    for (int jt = 0; jt < 4; ++jt) {
        #pragma unroll
        for (int kh = 0; kh < 2; ++kh) {
            bf16x8 bh = *(const bf16x8*)&woh[(jt * 16 + m) * WOS + kh * 32 + quad * 8];
            bf16x8 bl = *(const bf16x8*)&wol[(jt * 16 + m) * WOS + kh * 32 + quad * 8];
            acc[jt] = MFMA_BF16(ah[kh], bh, acc[jt], 0, 0, 0);
            acc[jt] = MFMA_BF16(al[kh], bh, acc[jt], 0, 0, 0);
            acc[jt] = MFMA_BF16(ah[kh], bl, acc[jt], 0, 0, 0);
        }
    }

    #pragma unroll
    for (int jt = 0; jt < 4; ++jt) {
        const float b = sb[jt * 16 + m];
        #pragma unroll
        for (int r = 0; r < 4; ++r)
            out[(p0 + r0 + quad * 4 + r) * 64 + jt * 16 + m] = acc[jt][r] + b;
    }
}

// ---------------------------------------------------------------------------
extern "C" void kernel_launch(void* const* d_in, const int* in_sizes, int n_in,
                              void* d_out, int out_size, void* d_ws, size_t ws_size,
                              hipStream_t stream)
{
    (void)in_sizes; (void)n_in; (void)out_size; (void)ws_size;
    const float* values = (const float*)d_in[0];
    const float* keys   = (const float*)d_in[1];
    const float* query  = (const float*)d_in[2];
    const float* Wv     = (const float*)d_in[3];
    const float* Wk     = (const float*)d_in[4];
    const float* Wq     = (const float*)d_in[5];
    const float* Wo     = (const float*)d_in[6];
    const float* bo     = (const float*)d_in[7];

    const size_t TOT = (size_t)144 * N_NODES * 16;   // 2,359,296 bf16 per plane
    unsigned short* ws16 = (unsigned short*)d_ws;
    unsigned short* qhi  = ws16;
    unsigned short* qlo  = ws16 + 1*TOT;
    unsigned short* khi  = ws16 + 2*TOT;
    unsigned short* klo  = ws16 + 3*TOT;
    unsigned short* vthi = ws16 + 4*TOT;
    unsigned short* vtlo = ws16 + 5*TOT;
    unsigned short* obh  = ws16 + 6*TOT;
    unsigned short* obl  = ws16 + 7*TOT;             // total ws = 8*TOT*2B = 37.75 MB

    // 288 = 16 n-tiles x 18 t-tiles; y = matrix (0=v,1=k,2=q)
    proj6_kernel<<<dim3(288, 3), 512, 0, stream>>>(values, keys, query, Wv, Wk, Wq,
                                                   qhi, qlo, khi, klo, vthi, vtlo);
    // 1152 = 144 th x 8 q-tiles of 128 rows — all co-resident, no tail
    attn_mfma9_kernel<<<dim3(8 * 144), 256, 0, stream>>>(qhi, qlo, khi, klo, vthi, vtlo,
                                                         obh, obl);
    outproj_mfma_kernel<<<dim3(576), 256, 0, stream>>>(obh, obl, Wo, bo, (float*)d_out);
}